// Round 9
// baseline (110.041 us; speedup 1.0000x reference)
//
#include <hip/hip_runtime.h>

#define N_DIM 4096
#define NE    16            // n split 16 ways -> 256 cols/block, 4 chunks of 64

typedef float f4  __attribute__((ext_vector_type(4)));
typedef short s8v __attribute__((ext_vector_type(8)));

#if defined(__has_builtin)
#if __has_builtin(__builtin_amdgcn_cvt_pk_bf16_f32)
#define HAVE_CVT_PK 1
#endif
#endif

static __device__ __forceinline__ unsigned int f2bf_pair(float lo, float hi) {
#ifdef HAVE_CVT_PK
    typedef __bf16 bf2 __attribute__((ext_vector_type(2)));
    bf2 p = __builtin_amdgcn_cvt_pk_bf16_f32(lo, hi);
    return __builtin_bit_cast(unsigned int, p);
#else
    unsigned int ul = __builtin_bit_cast(unsigned int, lo);
    unsigned int uh = __builtin_bit_cast(unsigned int, hi);
    ul = ul + 0x7fffu + ((ul >> 16) & 1u);
    uh = uh + 0x7fffu + ((uh >> 16) & 1u);
    return (uh & 0xffff0000u) | (ul >> 16);
#endif
}

static __device__ __forceinline__ s8v cvt8(f4 a, f4 b) {
    unsigned int u4[4] = { f2bf_pair(a[0], a[1]), f2bf_pair(a[2], a[3]),
                           f2bf_pair(b[0], b[1]), f2bf_pair(b[2], b[3]) };
    return __builtin_bit_cast(s8v, u4);
}

#define MFMA(a, b, c) __builtin_amdgcn_mfma_f32_16x16x32_bf16((a), (b), (c), 0, 0, 0)

// R8 structure (XOR-swizzled conflict-free LDS, raw lgkm-only barrier, no
// fences) + prefetch distance 2: preload chunks 0,1; at chunk c convert slot
// c&1 and issue chunk c+2 into that slot. Steady-state wait is vmcnt(8) with
// a full chunk (~1500 cyc) of slack — R8's distance-1 gave only ~600.
__global__ __launch_bounds__(256) void gemm_part_kernel(
    const float* __restrict__ zs, const float* __restrict__ X,
    float* __restrict__ part) {
    __shared__ s8v zsP[2][512];   // 64 k x 64 n bf16, dbuf (16 KB)
    __shared__ s8v xP [2][512];   // 64 i x 64 n bf16, dbuf (16 KB)

    const int tid  = threadIdx.x;
    const int lane = tid & 63;
    const int w    = tid >> 6;
    const int n0   = blockIdx.x * 256;
    const int i0   = blockIdx.y * 64;

    const int r0  = tid >> 3;
    const int c8w = tid & 7;
    const int g0  = r0 * 8 + (c8w ^ (r0 & 7));   // XOR swizzle (R8-verified)
    const int g1  = g0 + 256;

    const float* gz0 = zs + (size_t)r0 * N_DIM + n0 + c8w * 8;
    const float* gz1 = gz0 + (size_t)32 * N_DIM;
    const float* gx0 = X  + (size_t)(i0 + r0) * N_DIM + n0 + c8w * 8;
    const float* gx1 = gx0 + (size_t)32 * N_DIM;

    f4 rz[2][4], rx[2][4];
    #pragma unroll
    for (int p = 0; p < 2; ++p) {
        const int off = p * 64;
        rz[p][0] = *(const f4*)(gz0 + off); rz[p][1] = *(const f4*)(gz0 + off + 4);
        rz[p][2] = *(const f4*)(gz1 + off); rz[p][3] = *(const f4*)(gz1 + off + 4);
        rx[p][0] = *(const f4*)(gx0 + off); rx[p][1] = *(const f4*)(gx0 + off + 4);
        rx[p][2] = *(const f4*)(gx1 + off); rx[p][3] = *(const f4*)(gx1 + off + 4);
    }

    f4 acc[2][2] = {};
    const int kh  = (w & 1) * 2;
    const int ih  = (w >> 1) * 2;
    const int u0  = (lane & 15) * 8;
    const int xs0 = (lane >> 4) ^ (lane & 7);
    const int xs1 = xs0 ^ 4;

    #pragma unroll
    for (int c = 0; c < 4; ++c) {
        const int buf = c & 1;
        s8v pz0 = cvt8(rz[buf][0], rz[buf][1]);
        s8v pz1 = cvt8(rz[buf][2], rz[buf][3]);
        s8v px0 = cvt8(rx[buf][0], rx[buf][1]);
        s8v px1 = cvt8(rx[buf][2], rx[buf][3]);
        if (c < 2) {   // issue chunk c+2 into the slot just consumed
            const int off = (c + 2) * 64;
            rz[buf][0] = *(const f4*)(gz0 + off); rz[buf][1] = *(const f4*)(gz0 + off + 4);
            rz[buf][2] = *(const f4*)(gz1 + off); rz[buf][3] = *(const f4*)(gz1 + off + 4);
            rx[buf][0] = *(const f4*)(gx0 + off); rx[buf][1] = *(const f4*)(gx0 + off + 4);
            rx[buf][2] = *(const f4*)(gx1 + off); rx[buf][3] = *(const f4*)(gx1 + off + 4);
        }
        zsP[buf][g0] = pz0;  zsP[buf][g1] = pz1;
        xP[buf][g0]  = px0;  xP[buf][g1]  = px1;
        asm volatile("s_waitcnt lgkmcnt(0)\n\ts_barrier" ::: "memory");

        s8v a0s0 = zsP[buf][(kh    ) * 128 + u0 + xs0];
        s8v a0s1 = zsP[buf][(kh    ) * 128 + u0 + xs1];
        s8v a1s0 = zsP[buf][(kh + 1) * 128 + u0 + xs0];
        s8v a1s1 = zsP[buf][(kh + 1) * 128 + u0 + xs1];
        s8v b0s0 = xP [buf][(ih    ) * 128 + u0 + xs0];
        s8v b0s1 = xP [buf][(ih    ) * 128 + u0 + xs1];
        s8v b1s0 = xP [buf][(ih + 1) * 128 + u0 + xs0];
        s8v b1s1 = xP [buf][(ih + 1) * 128 + u0 + xs1];

        acc[0][0] = MFMA(a0s0, b0s0, acc[0][0]);
        acc[0][1] = MFMA(a0s0, b1s0, acc[0][1]);
        acc[1][0] = MFMA(a1s0, b0s0, acc[1][0]);
        acc[1][1] = MFMA(a1s0, b1s0, acc[1][1]);
        acc[0][0] = MFMA(a0s1, b0s1, acc[0][0]);
        acc[0][1] = MFMA(a0s1, b1s1, acc[0][1]);
        acc[1][0] = MFMA(a1s1, b0s1, acc[1][0]);
        acc[1][1] = MFMA(a1s1, b1s1, acc[1][1]);
    }

    // partial store: [it][ne][j], j = (ktile*4 + itile)*64 + lane — consumer-dense
    f4* pp = (f4*)part;
    const int tb = (blockIdx.y * NE + blockIdx.x) * 1024;
    #pragma unroll
    for (int a = 0; a < 2; ++a)
        #pragma unroll
        for (int b = 0; b < 2; ++b)
            pp[tb + ((kh + a) * 4 + (ih + b)) * 64 + lane] = acc[a][b];
}

// Epilogue on 256 blocks: grid (4 k-quarters, 64 i-tiles); one f4 granule per
// thread summed over the 16 ne partials (dense 16 B/lane), exact-fp32 num/den,
// one atomic per block. Same 16 MB traffic as R8's version on 4x the CUs.
__global__ __launch_bounds__(256) void epilogue_kernel(
    const float* __restrict__ part, const float* __restrict__ zs,
    const float* __restrict__ X, const float* __restrict__ varp,
    float* __restrict__ out) {
    const int tid  = threadIdx.x;
    const int lane = tid & 63;
    const int w    = tid >> 6;
    const int q    = blockIdx.x;     // k-quarter == ktile (j>>8)
    const int it   = blockIdx.y;
    const f4* pp   = (const f4*)part;

    f4 s = {};
    const int jj = q * 256 + tid;
    #pragma unroll 4
    for (int ne = 0; ne < NE; ++ne) {
        f4 v = pp[(it * NE + ne) * 1024 + jj];
        s[0] += v[0]; s[1] += v[1]; s[2] += v[2]; s[3] += v[3];
    }
    // decode: itl = w, ln = lane; C/D: col = lane&15 (i), row = (lane>>4)*4 + r (k)
    const int   i   = it * 64 + w * 16 + (lane & 15);
    const int   k0  = q * 16 + (lane >> 4) * 4;
    const float dg  = X[(size_t)i * (N_DIM + 1)];
    const float var = varp[0];

    float vsum = 0.f;
    #pragma unroll
    for (int r = 0; r < 4; ++r) {
        float num = zs[(size_t)(k0 + r) * N_DIM + i] * dg;   // exact fp32
        float den = s[r] - num;
        vsum += num / (var + den);
    }
    #pragma unroll
    for (int off = 32; off >= 1; off >>= 1) vsum += __shfl_down(vsum, off);
    __shared__ float wsum[4];
    if (lane == 0) wsum[w] = vsum;
    __syncthreads();
    if (tid == 0)
        atomicAdd(out, -(wsum[0] + wsum[1] + wsum[2] + wsum[3]) * (1.0f / 64.0f));
}

extern "C" void kernel_launch(void* const* d_in, const int* in_sizes, int n_in,
                              void* d_out, int out_size, void* d_ws, size_t ws_size,
                              hipStream_t stream) {
    const float* zs   = (const float*)d_in[0];
    const float* X    = (const float*)d_in[1];
    const float* varp = (const float*)d_in[2];
    float* out  = (float*)d_out;
    float* part = (float*)d_ws;     // 64 it x 16 ne x 16 KB = 16 MB

    hipMemsetAsync(out, 0, sizeof(float), stream);   // graph-capture-safe
    hipLaunchKernelGGL(gemm_part_kernel, dim3(NE, 64), dim3(256), 0, stream, zs, X, part);
    hipLaunchKernelGGL(epilogue_kernel, dim3(4, 64), dim3(256), 0, stream,
                       part, zs, X, varp, out);
}

// Round 10
// 107.595 us; speedup vs baseline: 1.0227x; 1.0227x over previous
//
#include <hip/hip_runtime.h>

#define N_DIM 4096
#define NE    16            // n split 16 ways -> 256 cols/block, 4 chunks of 64

typedef float f4  __attribute__((ext_vector_type(4)));
typedef short s8v __attribute__((ext_vector_type(8)));

#if defined(__has_builtin)
#if __has_builtin(__builtin_amdgcn_cvt_pk_bf16_f32)
#define HAVE_CVT_PK 1
#endif
#endif

static __device__ __forceinline__ unsigned int f2bf_pair(float lo, float hi) {
#ifdef HAVE_CVT_PK
    typedef __bf16 bf2 __attribute__((ext_vector_type(2)));
    bf2 p = __builtin_amdgcn_cvt_pk_bf16_f32(lo, hi);
    return __builtin_bit_cast(unsigned int, p);
#else
    unsigned int ul = __builtin_bit_cast(unsigned int, lo);
    unsigned int uh = __builtin_bit_cast(unsigned int, hi);
    ul = ul + 0x7fffu + ((ul >> 16) & 1u);
    uh = uh + 0x7fffu + ((uh >> 16) & 1u);
    return (uh & 0xffff0000u) | (ul >> 16);
#endif
}

static __device__ __forceinline__ s8v cvt8(f4 a, f4 b) {
    unsigned int u4[4] = { f2bf_pair(a[0], a[1]), f2bf_pair(a[2], a[3]),
                           f2bf_pair(b[0], b[1]), f2bf_pair(b[2], b[3]) };
    return __builtin_bit_cast(s8v, u4);
}

#define MFMA(a, b, c) __builtin_amdgcn_mfma_f32_16x16x32_bf16((a), (b), (c), 0, 0, 0)

// R9 gemm (XOR-swizzled conflict-free LDS, raw lgkm-only barrier, prefetch
// distance 2, no fences) + out-zeroing folded in (block (0,0) writes out=0;
// the epilogue's atomics are in the NEXT stream-ordered dispatch — safe).
__global__ __launch_bounds__(256) void gemm_part_kernel(
    const float* __restrict__ zs, const float* __restrict__ X,
    float* __restrict__ part, float* __restrict__ out) {
    __shared__ s8v zsP[2][512];   // 64 k x 64 n bf16, dbuf (16 KB)
    __shared__ s8v xP [2][512];   // 64 i x 64 n bf16, dbuf (16 KB)

    const int tid  = threadIdx.x;
    const int lane = tid & 63;
    const int w    = tid >> 6;
    const int n0   = blockIdx.x * 256;
    const int i0   = blockIdx.y * 64;

    if (blockIdx.x == 0 && blockIdx.y == 0 && tid == 0) *out = 0.f;

    const int r0  = tid >> 3;
    const int c8w = tid & 7;
    const int g0  = r0 * 8 + (c8w ^ (r0 & 7));   // XOR swizzle (R8-verified)
    const int g1  = g0 + 256;

    const float* gz0 = zs + (size_t)r0 * N_DIM + n0 + c8w * 8;
    const float* gz1 = gz0 + (size_t)32 * N_DIM;
    const float* gx0 = X  + (size_t)(i0 + r0) * N_DIM + n0 + c8w * 8;
    const float* gx1 = gx0 + (size_t)32 * N_DIM;

    f4 rz[2][4], rx[2][4];
    #pragma unroll
    for (int p = 0; p < 2; ++p) {
        const int off = p * 64;
        rz[p][0] = *(const f4*)(gz0 + off); rz[p][1] = *(const f4*)(gz0 + off + 4);
        rz[p][2] = *(const f4*)(gz1 + off); rz[p][3] = *(const f4*)(gz1 + off + 4);
        rx[p][0] = *(const f4*)(gx0 + off); rx[p][1] = *(const f4*)(gx0 + off + 4);
        rx[p][2] = *(const f4*)(gx1 + off); rx[p][3] = *(const f4*)(gx1 + off + 4);
    }

    f4 acc[2][2] = {};
    const int kh  = (w & 1) * 2;
    const int ih  = (w >> 1) * 2;
    const int u0  = (lane & 15) * 8;
    const int xs0 = (lane >> 4) ^ (lane & 7);
    const int xs1 = xs0 ^ 4;

    #pragma unroll
    for (int c = 0; c < 4; ++c) {
        const int buf = c & 1;
        s8v pz0 = cvt8(rz[buf][0], rz[buf][1]);
        s8v pz1 = cvt8(rz[buf][2], rz[buf][3]);
        s8v px0 = cvt8(rx[buf][0], rx[buf][1]);
        s8v px1 = cvt8(rx[buf][2], rx[buf][3]);
        if (c < 2) {   // issue chunk c+2 into the slot just consumed
            const int off = (c + 2) * 64;
            rz[buf][0] = *(const f4*)(gz0 + off); rz[buf][1] = *(const f4*)(gz0 + off + 4);
            rz[buf][2] = *(const f4*)(gz1 + off); rz[buf][3] = *(const f4*)(gz1 + off + 4);
            rx[buf][0] = *(const f4*)(gx0 + off); rx[buf][1] = *(const f4*)(gx0 + off + 4);
            rx[buf][2] = *(const f4*)(gx1 + off); rx[buf][3] = *(const f4*)(gx1 + off + 4);
        }
        zsP[buf][g0] = pz0;  zsP[buf][g1] = pz1;
        xP[buf][g0]  = px0;  xP[buf][g1]  = px1;
        asm volatile("s_waitcnt lgkmcnt(0)\n\ts_barrier" ::: "memory");

        s8v a0s0 = zsP[buf][(kh    ) * 128 + u0 + xs0];
        s8v a0s1 = zsP[buf][(kh    ) * 128 + u0 + xs1];
        s8v a1s0 = zsP[buf][(kh + 1) * 128 + u0 + xs0];
        s8v a1s1 = zsP[buf][(kh + 1) * 128 + u0 + xs1];
        s8v b0s0 = xP [buf][(ih    ) * 128 + u0 + xs0];
        s8v b0s1 = xP [buf][(ih    ) * 128 + u0 + xs1];
        s8v b1s0 = xP [buf][(ih + 1) * 128 + u0 + xs0];
        s8v b1s1 = xP [buf][(ih + 1) * 128 + u0 + xs1];

        acc[0][0] = MFMA(a0s0, b0s0, acc[0][0]);
        acc[0][1] = MFMA(a0s0, b1s0, acc[0][1]);
        acc[1][0] = MFMA(a1s0, b0s0, acc[1][0]);
        acc[1][1] = MFMA(a1s0, b1s0, acc[1][1]);
        acc[0][0] = MFMA(a0s1, b0s1, acc[0][0]);
        acc[0][1] = MFMA(a0s1, b1s1, acc[0][1]);
        acc[1][0] = MFMA(a1s1, b0s1, acc[1][0]);
        acc[1][1] = MFMA(a1s1, b1s1, acc[1][1]);
    }

    // partial store: [it][ne][j], j = (ktile*4 + itile)*64 + lane — consumer-dense
    f4* pp = (f4*)part;
    const int tb = (blockIdx.y * NE + blockIdx.x) * 1024;
    #pragma unroll
    for (int a = 0; a < 2; ++a)
        #pragma unroll
        for (int b = 0; b < 2; ++b)
            pp[tb + ((kh + a) * 4 + (ih + b)) * 64 + lane] = acc[a][b];
}

// Epilogue: grid (4 k-quarters, 64 i-tiles); one f4 granule per thread summed
// over the 16 ne partials (dense 16 B/lane), exact-fp32 num/den, one atomic
// per block.
__global__ __launch_bounds__(256) void epilogue_kernel(
    const float* __restrict__ part, const float* __restrict__ zs,
    const float* __restrict__ X, const float* __restrict__ varp,
    float* __restrict__ out) {
    const int tid  = threadIdx.x;
    const int lane = tid & 63;
    const int w    = tid >> 6;
    const int q    = blockIdx.x;     // k-quarter == ktile (j>>8)
    const int it   = blockIdx.y;
    const f4* pp   = (const f4*)part;

    f4 s = {};
    const int jj = q * 256 + tid;
    #pragma unroll 4
    for (int ne = 0; ne < NE; ++ne) {
        f4 v = pp[(it * NE + ne) * 1024 + jj];
        s[0] += v[0]; s[1] += v[1]; s[2] += v[2]; s[3] += v[3];
    }
    // decode: itl = w; C/D: col = lane&15 (i), row = (lane>>4)*4 + r (k)
    const int   i   = it * 64 + w * 16 + (lane & 15);
    const int   k0  = q * 16 + (lane >> 4) * 4;
    const float dg  = X[(size_t)i * (N_DIM + 1)];
    const float var = varp[0];

    float vsum = 0.f;
    #pragma unroll
    for (int r = 0; r < 4; ++r) {
        float num = zs[(size_t)(k0 + r) * N_DIM + i] * dg;   // exact fp32
        float den = s[r] - num;
        vsum += num / (var + den);
    }
    #pragma unroll
    for (int off = 32; off >= 1; off >>= 1) vsum += __shfl_down(vsum, off);
    __shared__ float wsum[4];
    if (lane == 0) wsum[w] = vsum;
    __syncthreads();
    if (tid == 0)
        atomicAdd(out, -(wsum[0] + wsum[1] + wsum[2] + wsum[3]) * (1.0f / 64.0f));
}

extern "C" void kernel_launch(void* const* d_in, const int* in_sizes, int n_in,
                              void* d_out, int out_size, void* d_ws, size_t ws_size,
                              hipStream_t stream) {
    const float* zs   = (const float*)d_in[0];
    const float* X    = (const float*)d_in[1];
    const float* varp = (const float*)d_in[2];
    float* out  = (float*)d_out;
    float* part = (float*)d_ws;     // 64 it x 16 ne x 16 KB = 16 MB

    hipLaunchKernelGGL(gemm_part_kernel, dim3(NE, 64), dim3(256), 0, stream,
                       zs, X, part, out);
    hipLaunchKernelGGL(epilogue_kernel, dim3(4, 64), dim3(256), 0, stream,
                       part, zs, X, varp, out);
}